// Round 1
// baseline (5994.550 us; speedup 1.0000x reference)
//
#include <hip/hip_runtime.h>

typedef __attribute__((ext_vector_type(8))) short bf16x8;
typedef __attribute__((ext_vector_type(4))) short bf16x4;
typedef __attribute__((ext_vector_type(4))) float f32x4;

__device__ __forceinline__ short f2bf(float f) {
  union { float f; unsigned u; } v; v.f = f;
  unsigned r = v.u + 0x7fffu + ((v.u >> 16) & 1u);
  return (short)(r >> 16);
}
__device__ __forceinline__ float sigm(float x) {
  float e = exp2f(-1.44269504f * x);
  return __builtin_amdgcn_rcpf(1.0f + e);
}
__device__ __forceinline__ float tanh_f(float x) {
  float a = __builtin_fabsf(x);
  float t = exp2f(-2.88539008f * a);            // e^{-2|x|} in (0,1] -> no overflow for large c
  float r = (1.0f - t) * __builtin_amdgcn_rcpf(1.0f + t);
  return __builtin_copysignf(r, x);
}

// ---------------- weight packing: fp32 -> bf16 MFMA B-fragment order ----------------
// wp layout (16B slots): [0,32768): W_hh1 ; [32768,65536): W_ih1 ; [65536,81920): W_ih2 ; [81920,90112): W_hh2
// B-frag for mfma_f32_16x16x32_bf16: lane l holds B[k = kc*32+(l>>4)*8+e][col = C0+(l&15)], e=0..7
__global__ __launch_bounds__(256) void pack_w(
    const float* __restrict__ W_ih1, const float* __restrict__ W_hh1,
    const float* __restrict__ W_ih2, const float* __restrict__ W_hh2,
    short* __restrict__ wp) {
  int s = blockIdx.x * 256 + threadIdx.x;
  if (s >= 90112) return;
  const float* src; int col, k0, K;
  if (s < 32768) {
    int w = s >> 12, grp = (s >> 9) & 7, kc = (s >> 6) & 7, l = s & 63;
    col = (grp & 3) * 256 + w * 32 + (grp >> 2) * 16 + (l & 15);
    k0 = kc * 32 + (l >> 4) * 8; K = 256; src = W_hh1;
  } else if (s < 65536) {
    int s2 = s - 32768;
    int w = s2 >> 12, grp = (s2 >> 9) & 7, kc = (s2 >> 6) & 7, l = s2 & 63;
    col = (grp & 3) * 256 + w * 32 + (grp >> 2) * 16 + (l & 15);
    k0 = kc * 32 + (l >> 4) * 8; K = 256; src = W_ih1;
  } else if (s < 81920) {
    int s3 = s - 65536;
    int w = s3 >> 11, gate = (s3 >> 9) & 3, kc = (s3 >> 6) & 7, l = s3 & 63;
    col = gate * 128 + w * 16 + (l & 15);
    k0 = kc * 32 + (l >> 4) * 8; K = 256; src = W_ih2;
  } else {
    int s4 = s - 81920;
    int w = s4 >> 10, gate = (s4 >> 8) & 3, kc = (s4 >> 6) & 3, l = s4 & 63;
    col = gate * 128 + w * 16 + (l & 15);
    k0 = kc * 32 + (l >> 4) * 8; K = 128; src = W_hh2;
  }
  const float* p = src + (size_t)col * K + k0;
  bf16x8 o;
  #pragma unroll
  for (int e = 0; e < 8; ++e) o[e] = f2bf(p[e]);
  *(bf16x8*)(wp + (size_t)s * 8) = o;
}

// ---------------- persistent 2-layer LSTM ----------------
// 128 blocks x 512 threads (8 waves). Block owns 32 batch rows for all 128 steps.
// Wave w: layer1 hidden units [32w,32w+32) (2 col-subtiles x 4 gates), layer2 units [16w,16w+16).
// LDS: x1 fp32 acc-packed 128KB | h0 bf16 swizzled 16KB | h1 bf16 swizzled 8KB = 152KB -> 1 block/CU.
__global__ __launch_bounds__(512, 2) void lstm_persist(
    const float* __restrict__ emb,
    const float* __restrict__ b_ih1, const float* __restrict__ b_hh1,
    const float* __restrict__ b_ih2, const float* __restrict__ b_hh2,
    const short* __restrict__ wp,
    float* __restrict__ out) {
  extern __shared__ __align__(16) char lds[];
  char* x1lds = lds;                  // 131072 B
  char* h0lds = lds + (128 << 10);    // 16384 B : [32 rows][256 units] bf16, byte ^= (row&7)<<4
  char* h1lds = lds + (144 << 10);    // 8192 B  : [32 rows][128 units] bf16, same swizzle

  const int tid = threadIdx.x;
  const int w = tid >> 6;
  const int l = tid & 63;
  const int l15 = l & 15, l4 = l >> 4;
  const int rowb = blockIdx.x * 32;

  const short* W1h = wp;
  const short* W1i = wp + 32768 * 8;
  const short* W2a = wp + 65536 * 8;
  const short* W2b = wp + 81920 * 8;

  // ---- stage emb rows -> h0lds as bf16 (swizzled) ----
  #pragma unroll
  for (int it = 0; it < 4; ++it) {
    int flat = it * 2048 + tid * 4;
    int r = flat >> 8, c = flat & 255;
    f32x4 v = *(const f32x4*)(emb + (size_t)(rowb + r) * 256 + c);
    bf16x4 b;
    #pragma unroll
    for (int e = 0; e < 4; ++e) b[e] = f2bf(v[e]);
    int byte = (r * 512 + c * 2) ^ ((r & 7) << 4);
    *(bf16x4*)(h0lds + byte) = b;
  }
  __syncthreads();

  bf16x8 a0[2][8];   // layer1/2 K=256 A-frags (h0 / emb)
  bf16x8 a1[2][4];   // layer2 K=128 A-frags (h1)

  // read emb frags
  #pragma unroll
  for (int m = 0; m < 2; ++m)
    #pragma unroll
    for (int kc = 0; kc < 8; ++kc) {
      int rr = m * 16 + l15;
      int byte = (rr * 512 + kc * 64 + l4 * 16) ^ ((rr & 7) << 4);
      a0[m][kc] = *(const bf16x8*)(h0lds + byte);
    }

  // ---- x1 = emb @ W_ih1^T + (b_ih1+b_hh1), parked in LDS in accumulator layout ----
  #pragma unroll
  for (int grp = 0; grp < 8; ++grp) {
    int gate = grp & 3, cs = grp >> 2;
    int col = gate * 256 + w * 32 + cs * 16 + l15;
    float bv = b_ih1[col] + b_hh1[col];
    f32x4 acc0 = {bv, bv, bv, bv}, acc1 = {bv, bv, bv, bv};
    #pragma unroll
    for (int kc = 0; kc < 8; ++kc) {
      bf16x8 bb = *(const bf16x8*)(W1i + ((w * 8 + grp) * 8 + kc) * 512 + l * 8);
      acc0 = __builtin_amdgcn_mfma_f32_16x16x32_bf16(a0[0][kc], bb, acc0, 0, 0, 0);
      acc1 = __builtin_amdgcn_mfma_f32_16x16x32_bf16(a0[1][kc], bb, acc1, 0, 0, 0);
    }
    *(f32x4*)(x1lds + (w * 16 + grp * 2 + 0) * 1024 + l * 16) = acc0;
    *(f32x4*)(x1lds + (w * 16 + grp * 2 + 1) * 1024 + l * 16) = acc1;
  }
  __syncthreads();

  // zero recurrent state
  const bf16x8 ZB = {0, 0, 0, 0, 0, 0, 0, 0};
  #pragma unroll
  for (int m = 0; m < 2; ++m) {
    #pragma unroll
    for (int kc = 0; kc < 8; ++kc) a0[m][kc] = ZB;
    #pragma unroll
    for (int kc = 0; kc < 4; ++kc) a1[m][kc] = ZB;
  }
  f32x4 c0[2][2] = {};   // [m][cs]
  f32x4 c1[2] = {};      // [m]

  float bias2[4];
  #pragma unroll
  for (int gate = 0; gate < 4; ++gate) {
    int col = gate * 128 + w * 16 + l15;
    bias2[gate] = b_ih2[col] + b_hh2[col];
  }

  #pragma unroll 1
  for (int t = 0; t < 128; ++t) {
    // ---------- layer 1: gates1 = x1 + h0 @ W_hh1^T ----------
    #pragma unroll
    for (int cs = 0; cs < 2; ++cs) {
      f32x4 g1[4][2];
      #pragma unroll
      for (int gate = 0; gate < 4; ++gate) {
        int grp = cs * 4 + gate;
        f32x4 acc0 = *(const f32x4*)(x1lds + (w * 16 + grp * 2 + 0) * 1024 + l * 16);
        f32x4 acc1 = *(const f32x4*)(x1lds + (w * 16 + grp * 2 + 1) * 1024 + l * 16);
        #pragma unroll
        for (int kc = 0; kc < 8; ++kc) {
          bf16x8 bb = *(const bf16x8*)(W1h + ((w * 8 + grp) * 8 + kc) * 512 + l * 8);
          acc0 = __builtin_amdgcn_mfma_f32_16x16x32_bf16(a0[0][kc], bb, acc0, 0, 0, 0);
          acc1 = __builtin_amdgcn_mfma_f32_16x16x32_bf16(a0[1][kc], bb, acc1, 0, 0, 0);
        }
        g1[gate][0] = acc0; g1[gate][1] = acc1;
      }
      #pragma unroll
      for (int m = 0; m < 2; ++m)
        #pragma unroll
        for (int r = 0; r < 4; ++r) {
          float gi = g1[0][m][r], gf = g1[1][m][r], gg = g1[2][m][r], go = g1[3][m][r];
          float c = sigm(gf) * c0[m][cs][r] + sigm(gi) * tanh_f(gg);
          c0[m][cs][r] = c;
          float h = sigm(go) * tanh_f(c);
          int rr = m * 16 + l4 * 4 + r;
          int byte = (rr * 512 + (w * 32 + cs * 16 + l15) * 2) ^ ((rr & 7) << 4);
          *(short*)(h0lds + byte) = f2bf(h);
        }
    }
    __syncthreads();   // h0(t) published
    #pragma unroll
    for (int m = 0; m < 2; ++m)
      #pragma unroll
      for (int kc = 0; kc < 8; ++kc) {
        int rr = m * 16 + l15;
        int byte = (rr * 512 + kc * 64 + l4 * 16) ^ ((rr & 7) << 4);
        a0[m][kc] = *(const bf16x8*)(h0lds + byte);
      }

    // ---------- layer 2: gates2 = h0 @ W_ih2^T + b2 + h1 @ W_hh2^T ----------
    f32x4 g2[4][2];
    #pragma unroll
    for (int gate = 0; gate < 4; ++gate) {
      float bv = bias2[gate];
      f32x4 acc0 = {bv, bv, bv, bv}, acc1 = {bv, bv, bv, bv};
      #pragma unroll
      for (int kc = 0; kc < 8; ++kc) {
        bf16x8 bb = *(const bf16x8*)(W2a + ((w * 4 + gate) * 8 + kc) * 512 + l * 8);
        acc0 = __builtin_amdgcn_mfma_f32_16x16x32_bf16(a0[0][kc], bb, acc0, 0, 0, 0);
        acc1 = __builtin_amdgcn_mfma_f32_16x16x32_bf16(a0[1][kc], bb, acc1, 0, 0, 0);
      }
      #pragma unroll
      for (int kc = 0; kc < 4; ++kc) {
        bf16x8 bb = *(const bf16x8*)(W2b + ((w * 4 + gate) * 4 + kc) * 512 + l * 8);
        acc0 = __builtin_amdgcn_mfma_f32_16x16x32_bf16(a1[0][kc], bb, acc0, 0, 0, 0);
        acc1 = __builtin_amdgcn_mfma_f32_16x16x32_bf16(a1[1][kc], bb, acc1, 0, 0, 0);
      }
      g2[gate][0] = acc0; g2[gate][1] = acc1;
    }
    float hout[2][4];
    #pragma unroll
    for (int m = 0; m < 2; ++m)
      #pragma unroll
      for (int r = 0; r < 4; ++r) {
        float gi = g2[0][m][r], gf = g2[1][m][r], gg = g2[2][m][r], go = g2[3][m][r];
        float c = sigm(gf) * c1[m][r] + sigm(gi) * tanh_f(gg);
        c1[m][r] = c;
        float h = sigm(go) * tanh_f(c);
        hout[m][r] = h;
        int rr = m * 16 + l4 * 4 + r;
        int byte = (rr * 256 + (w * 16 + l15) * 2) ^ ((rr & 7) << 4);
        *(short*)(h1lds + byte) = f2bf(h);
      }
    __syncthreads();   // h1(t) published
    // output stores overlap next phase-A
    #pragma unroll
    for (int m = 0; m < 2; ++m)
      #pragma unroll
      for (int r = 0; r < 4; ++r) {
        int grow = rowb + m * 16 + l4 * 4 + r;
        out[(size_t)grow * 16384 + (size_t)t * 128 + w * 16 + l15] = hout[m][r];
      }
    #pragma unroll
    for (int m = 0; m < 2; ++m)
      #pragma unroll
      for (int kc = 0; kc < 4; ++kc) {
        int rr = m * 16 + l15;
        int byte = (rr * 256 + kc * 64 + l4 * 16) ^ ((rr & 7) << 4);
        a1[m][kc] = *(const bf16x8*)(h1lds + byte);
      }
  }
}

extern "C" void kernel_launch(void* const* d_in, const int* in_sizes, int n_in,
                              void* d_out, int out_size, void* d_ws, size_t ws_size,
                              hipStream_t stream) {
  const float* emb   = (const float*)d_in[0];
  const float* W_ih1 = (const float*)d_in[1];
  const float* W_hh1 = (const float*)d_in[2];
  const float* b_ih1 = (const float*)d_in[3];
  const float* b_hh1 = (const float*)d_in[4];
  const float* W_ih2 = (const float*)d_in[5];
  const float* W_hh2 = (const float*)d_in[6];
  const float* b_ih2 = (const float*)d_in[7];
  const float* b_hh2 = (const float*)d_in[8];
  short* wp = (short*)d_ws;
  float* out = (float*)d_out;

  hipFuncSetAttribute((const void*)lstm_persist,
                      hipFuncAttributeMaxDynamicSharedMemorySize, 155648);
  pack_w<<<352, 256, 0, stream>>>(W_ih1, W_hh1, W_ih2, W_hh2, wp);
  lstm_persist<<<128, 512, 155648, stream>>>(emb, b_ih1, b_hh1, b_ih2, b_hh2, wp, out);
}

// Round 2
// 1876.708 us; speedup vs baseline: 3.1942x; 3.1942x over previous
//
#include <hip/hip_runtime.h>

typedef __attribute__((ext_vector_type(8))) short bf16x8;
typedef __attribute__((ext_vector_type(4))) float f32x4;

__device__ __forceinline__ short f2bf(float f) {
  union { float f; unsigned u; } v; v.f = f;
  unsigned r = v.u + 0x7fffu + ((v.u >> 16) & 1u);
  return (short)(r >> 16);
}
__device__ __forceinline__ float sigm(float x) {
  float e = exp2f(-1.44269504f * x);
  return __builtin_amdgcn_rcpf(1.0f + e);
}
__device__ __forceinline__ float tanh_f(float x) {
  float a = __builtin_fabsf(x);
  float t = exp2f(-2.88539008f * a);
  float r = (1.0f - t) * __builtin_amdgcn_rcpf(1.0f + t);
  return __builtin_copysignf(r, x);
}
__device__ __forceinline__ f32x4 splat4(float b){ f32x4 v = {b,b,b,b}; return v; }

// ws layout (shorts for wp):
//  R1  [16 mem][4 nf][8 kc][64 l][8 e]  W_hh1 packed  (512KB)
//  R2a [16][2 gh][8 kc][64][8]          W_ih2         (256KB)
//  R2b [16][2][4][64][8]                W_hh2         (128KB)
//  R1i [16][4][8][64][8]                W_ih1         (512KB)
#define R1S   0
#define R2AS  262144
#define R2BS  393216
#define R1IS  458752
#define CTRL_B 1441792            // claim[8] @ w0..7, ctr[g] @ w16+g
#define H0X_B  1445888            // [2][16 grp][256 row][256 u] bf16 = 4MB
#define H1X_B  5640192            // [2][16 grp][256 row][128 u] bf16 = 2MB

// gate-pair packing: tile col = ul*2 + gp ; gate = gh*2 + gp
__global__ __launch_bounds__(256) void pack_w(
    const float* __restrict__ W_ih1, const float* __restrict__ W_hh1,
    const float* __restrict__ W_ih2, const float* __restrict__ W_hh2,
    short* __restrict__ wp) {
  int s = blockIdx.x * 256 + threadIdx.x;
  if (blockIdx.x == 0 && threadIdx.x < 64)
    ((unsigned*)((char*)wp + CTRL_B))[threadIdx.x] = 0u;   // zero claim+ctrs each launch
  if (s >= 90112) return;
  const float* src; int row, K, k0, l;
  if (s < 32768) {            // R1 <- W_hh1 [1024][256]
    int mm = s >> 11, r = s & 2047, nf = r >> 9, kc = (r >> 6) & 7; l = r & 63;
    int a = nf >> 1, gh = nf & 1, ul = (l & 15) >> 1, gp = l & 1;
    row = (gh*2+gp)*256 + mm*16 + a*8 + ul; K = 256; k0 = kc*32 + (l>>4)*8; src = W_hh1;
  } else if (s < 49152) {     // R2a <- W_ih2 [512][256]
    int s2 = s - 32768, mm = s2 >> 10, r = s2 & 1023, gh = r >> 9, kc = (r >> 6) & 7; l = r & 63;
    int ul = (l & 15) >> 1, gp = l & 1;
    row = (gh*2+gp)*128 + mm*8 + ul; K = 256; k0 = kc*32 + (l>>4)*8; src = W_ih2;
  } else if (s < 57344) {     // R2b <- W_hh2 [512][128]
    int s3 = s - 49152, mm = s3 >> 9, r = s3 & 511, gh = r >> 8, kc = (r >> 6) & 3; l = r & 63;
    int ul = (l & 15) >> 1, gp = l & 1;
    row = (gh*2+gp)*128 + mm*8 + ul; K = 128; k0 = kc*32 + (l>>4)*8; src = W_hh2;
  } else {                    // R1i <- W_ih1 [1024][256]
    int s4 = s - 57344, mm = s4 >> 11, r = s4 & 2047, nf = r >> 9, kc = (r >> 6) & 7; l = r & 63;
    int a = nf >> 1, gh = nf & 1, ul = (l & 15) >> 1, gp = l & 1;
    row = (gh*2+gp)*256 + mm*16 + a*8 + ul; K = 256; k0 = kc*32 + (l>>4)*8; src = W_ih1;
  }
  const float* p = src + (size_t)row * K + k0;
  bf16x8 o;
  #pragma unroll
  for (int e = 0; e < 8; ++e) o[e] = f2bf(p[e]);
  *(bf16x8*)(wp + (size_t)s * 8) = o;
}

// 256 blocks x 512 threads, 1 block/CU (LDS-padded). 16 groups x 16 members.
// Group: 256 batch rows. Member: 16 L1 units (64 cols) + 8 L2 units (32 cols),
// weights in LDS (56KB). 8 waves x 32 rows (m=2). One group barrier per step.
__global__ __launch_bounds__(512, 2) void lstm_persist(
    const float* __restrict__ emb, const float* __restrict__ b_ih1,
    const float* __restrict__ b_hh1, const float* __restrict__ b_ih2,
    const float* __restrict__ b_hh2, char* __restrict__ ws,
    float* __restrict__ out) {
  extern __shared__ __align__(16) short ldsW[];
  const short* wp = (const short*)ws;
  unsigned* ctrl = (unsigned*)(ws + CTRL_B);
  __shared__ unsigned s_gm;
  const int tid = threadIdx.x, w = tid >> 6, l = tid & 63, l15 = l & 15, l4 = l >> 4;
  const int ul = l15 >> 1, gp = l15 & 1;

  // claim a (group, member) slot on this block's own XCD -> same-XCD groups
  if (tid == 0) {
    unsigned xcc;
    asm volatile("s_getreg_b32 %0, hwreg(HW_REG_XCC_ID)" : "=s"(xcc));
    xcc &= 7u;
    unsigned slot = atomicAdd(&ctrl[xcc], 1u);
    s_gm = ((xcc * 2u + ((slot >> 4) & 1u)) << 8) | (slot & 15u);
  }
  __syncthreads();
  const int group = s_gm >> 8, member = s_gm & 255;

  // copy this member's weight slices into LDS (56KB)
  {
    const char* wpB = (const char*)wp;
    #pragma unroll
    for (int it = 0; it < 7; ++it) {
      int byte = (tid + it * 512) * 16;
      const char* src;
      if (byte < 32768)      src = wpB + (size_t)R1S * 2  + member * 32768 + byte;
      else if (byte < 49152) src = wpB + (size_t)R2AS * 2 + member * 16384 + (byte - 32768);
      else                   src = wpB + (size_t)R2BS * 2 + member * 8192  + (byte - 49152);
      *(f32x4*)((char*)ldsW + byte) = *(const f32x4*)src;
    }
  }
  float b2[2];
  #pragma unroll
  for (int gh = 0; gh < 2; ++gh) {
    int rw = (gh*2+gp)*128 + member*8 + ul;
    b2[gh] = b_ih2[rw] + b_hh2[rw];
  }
  float b1[4];
  #pragma unroll
  for (int nf = 0; nf < 4; ++nf) {
    int rw = ((nf&1)*2+gp)*256 + member*16 + (nf>>1)*8 + ul;
    b1[nf] = b_ih1[rw] + b_hh1[rw];
  }
  __syncthreads();   // LDS weights ready

  // x1 = emb @ W_ih1^T + b1 for rows [group*256 + w*32, +32), kept in registers
  const int grow0 = group * 256;
  const int rw0 = w * 32;
  f32x4 x1[2][4];
  #pragma unroll
  for (int m = 0; m < 2; ++m)
    #pragma unroll
    for (int nf = 0; nf < 4; ++nf) x1[m][nf] = splat4(b1[nf]);
  #pragma unroll
  for (int kc = 0; kc < 8; ++kc) {
    bf16x8 af[2];
    #pragma unroll
    for (int m = 0; m < 2; ++m) {
      const float* ep = emb + (size_t)(grow0 + rw0 + m*16 + l15) * 256 + kc*32 + l4*8;
      f32x4 lo = *(const f32x4*)ep, hi = *(const f32x4*)(ep + 4);
      bf16x8 t8;
      #pragma unroll
      for (int e = 0; e < 4; ++e) { t8[e] = f2bf(lo[e]); t8[e+4] = f2bf(hi[e]); }
      af[m] = t8;
    }
    #pragma unroll
    for (int nf = 0; nf < 4; ++nf) {
      bf16x8 bb = *(const bf16x8*)(wp + R1IS + (((size_t)member*4 + nf)*8 + kc)*512 + l*8);
      x1[0][nf] = __builtin_amdgcn_mfma_f32_16x16x32_bf16(af[0], bb, x1[0][nf], 0, 0, 0);
      x1[1][nf] = __builtin_amdgcn_mfma_f32_16x16x32_bf16(af[1], bb, x1[1][nf], 0, 0, 0);
    }
  }

  bf16x8 a0[2][8];
  const bf16x8 ZB = {0,0,0,0,0,0,0,0};
  #pragma unroll
  for (int m = 0; m < 2; ++m)
    #pragma unroll
    for (int kc = 0; kc < 8; ++kc) a0[m][kc] = ZB;
  f32x4 c0[2][2] = {};
  f32x4 c1[2] = {};

  unsigned* myctr = &ctrl[16 + group];
  char* h0x = ws + H0X_B;
  char* h1x = ws + H1X_B;

  #pragma unroll 1
  for (int t = 0; t < 128; ++t) {
    // ---------- phase A: gates1 = x1 + h0(t-1) @ W_hh1^T ----------
    f32x4 acc1[2][4];
    #pragma unroll
    for (int m = 0; m < 2; ++m)
      #pragma unroll
      for (int nf = 0; nf < 4; ++nf) acc1[m][nf] = x1[m][nf];
    #pragma unroll
    for (int nf = 0; nf < 4; ++nf)
      #pragma unroll
      for (int kc = 0; kc < 8; ++kc) {
        bf16x8 bb = *(const bf16x8*)(ldsW + (nf*8 + kc)*512 + l*8);
        acc1[0][nf] = __builtin_amdgcn_mfma_f32_16x16x32_bf16(a0[0][kc], bb, acc1[0][nf], 0,0,0);
        acc1[1][nf] = __builtin_amdgcn_mfma_f32_16x16x32_bf16(a0[1][kc], bb, acc1[1][nf], 0,0,0);
      }
    char* h0w = h0x + ((size_t)(t & 1) * 16 + group) * 131072;
    #pragma unroll
    for (int m = 0; m < 2; ++m)
      #pragma unroll
      for (int a = 0; a < 2; ++a) {
        f32x4 v0 = acc1[m][a*2+0], v1 = acc1[m][a*2+1], p0, p1;
        #pragma unroll
        for (int r = 0; r < 4; ++r) { p0[r] = __shfl_xor(v0[r],1,64); p1[r] = __shfl_xor(v1[r],1,64); }
        #pragma unroll
        for (int r = 0; r < 4; ++r) {
          float iv = gp ? p0[r] : v0[r], fv = gp ? v0[r] : p0[r];
          float gv = gp ? p1[r] : v1[r], ov = gp ? v1[r] : p1[r];
          float c = sigm(fv) * c0[m][a][r] + sigm(iv) * tanh_f(gv);
          c0[m][a][r] = c;
          float h = sigm(ov) * tanh_f(c);
          if (!gp) {
            int row = rw0 + m*16 + l4*4 + r;
            *(short*)(h0w + row*512 + (member*16 + a*8 + ul)*2) = f2bf(h);
          }
        }
      }
    // ---------- group barrier (one per step) ----------
    __syncthreads();                       // drains vmcnt: h0 stores visible in L2
    if (tid == 0) {
      __hip_atomic_fetch_add(myctr, 1u, __ATOMIC_RELAXED, __HIP_MEMORY_SCOPE_AGENT);
      unsigned tgt = 16u * (t + 1); int z = 0;
      while (__hip_atomic_load(myctr, __ATOMIC_RELAXED, __HIP_MEMORY_SCOPE_AGENT) < tgt) {
        __builtin_amdgcn_s_sleep(8);
        if (++z > (1 << 17)) break;        // escape hatch: fail visibly, never hang
      }
    }
    __syncthreads();
    asm volatile("buffer_inv sc0\n\ts_waitcnt vmcnt(0)" ::: "memory");  // kill stale L1
    // ---------- phase B: gates2 = h0(t)@W_ih2^T + b2 + h1(t-1)@W_hh2^T ----------
    const char* h0r = h0x + ((size_t)(t & 1) * 16 + group) * 131072;
    #pragma unroll
    for (int m = 0; m < 2; ++m)
      #pragma unroll
      for (int kc = 0; kc < 8; ++kc)
        a0[m][kc] = *(const bf16x8*)(h0r + (rw0 + m*16 + l15)*512 + kc*64 + l4*16);
    bf16x8 a1[2][4];
    if (t > 0) {
      const char* h1r = h1x + ((size_t)((t-1) & 1) * 16 + group) * 65536;
      #pragma unroll
      for (int m = 0; m < 2; ++m)
        #pragma unroll
        for (int kc = 0; kc < 4; ++kc)
          a1[m][kc] = *(const bf16x8*)(h1r + (rw0 + m*16 + l15)*256 + kc*64 + l4*16);
    }
    f32x4 acc2[2][2];
    #pragma unroll
    for (int m = 0; m < 2; ++m)
      #pragma unroll
      for (int gh = 0; gh < 2; ++gh) acc2[m][gh] = splat4(b2[gh]);
    #pragma unroll
    for (int gh = 0; gh < 2; ++gh)
      #pragma unroll
      for (int kc = 0; kc < 8; ++kc) {
        bf16x8 bb = *(const bf16x8*)(ldsW + 16384 + (gh*8 + kc)*512 + l*8);
        acc2[0][gh] = __builtin_amdgcn_mfma_f32_16x16x32_bf16(a0[0][kc], bb, acc2[0][gh], 0,0,0);
        acc2[1][gh] = __builtin_amdgcn_mfma_f32_16x16x32_bf16(a0[1][kc], bb, acc2[1][gh], 0,0,0);
      }
    if (t > 0) {
      #pragma unroll
      for (int gh = 0; gh < 2; ++gh)
        #pragma unroll
        for (int kc = 0; kc < 4; ++kc) {
          bf16x8 bb = *(const bf16x8*)(ldsW + 24576 + (gh*4 + kc)*512 + l*8);
          acc2[0][gh] = __builtin_amdgcn_mfma_f32_16x16x32_bf16(a1[0][kc], bb, acc2[0][gh], 0,0,0);
          acc2[1][gh] = __builtin_amdgcn_mfma_f32_16x16x32_bf16(a1[1][kc], bb, acc2[1][gh], 0,0,0);
        }
    }
    char* h1w = h1x + ((size_t)(t & 1) * 16 + group) * 65536;
    #pragma unroll
    for (int m = 0; m < 2; ++m) {
      f32x4 v0 = acc2[m][0], v1 = acc2[m][1], p0, p1;
      #pragma unroll
      for (int r = 0; r < 4; ++r) { p0[r] = __shfl_xor(v0[r],1,64); p1[r] = __shfl_xor(v1[r],1,64); }
      #pragma unroll
      for (int r = 0; r < 4; ++r) {
        float iv = gp ? p0[r] : v0[r], fv = gp ? v0[r] : p0[r];
        float gv = gp ? p1[r] : v1[r], ov = gp ? v1[r] : p1[r];
        float c = sigm(fv) * c1[m][r] + sigm(iv) * tanh_f(gv);
        c1[m][r] = c;
        float h = sigm(ov) * tanh_f(c);
        if (!gp) {
          int row = rw0 + m*16 + l4*4 + r;
          *(short*)(h1w + row*256 + (member*8 + ul)*2) = f2bf(h);
          out[(size_t)(grow0 + row) * 16384 + t*128 + member*8 + ul] = h;
        }
      }
    }
  }
}

extern "C" void kernel_launch(void* const* d_in, const int* in_sizes, int n_in,
                              void* d_out, int out_size, void* d_ws, size_t ws_size,
                              hipStream_t stream) {
  const float* emb   = (const float*)d_in[0];
  const float* W_ih1 = (const float*)d_in[1];
  const float* W_hh1 = (const float*)d_in[2];
  const float* b_ih1 = (const float*)d_in[3];
  const float* b_hh1 = (const float*)d_in[4];
  const float* W_ih2 = (const float*)d_in[5];
  const float* W_hh2 = (const float*)d_in[6];
  const float* b_ih2 = (const float*)d_in[7];
  const float* b_hh2 = (const float*)d_in[8];
  char* ws = (char*)d_ws;
  float* out = (float*)d_out;

  hipFuncSetAttribute((const void*)lstm_persist,
                      hipFuncAttributeMaxDynamicSharedMemorySize, 98304);
  pack_w<<<352, 256, 0, stream>>>(W_ih1, W_hh1, W_ih2, W_hh2, (short*)d_ws);
  lstm_persist<<<256, 512, 98304, stream>>>(emb, b_ih1, b_hh1, b_ih2, b_hh2, ws, out);
}

// Round 3
// 1342.380 us; speedup vs baseline: 4.4656x; 1.3980x over previous
//
#include <hip/hip_runtime.h>

typedef __attribute__((ext_vector_type(8))) short bf16x8;
typedef __attribute__((ext_vector_type(4))) float f32x4;

__device__ __forceinline__ short f2bf(float f) {
  union { float f; unsigned u; } v; v.f = f;
  unsigned r = v.u + 0x7fffu + ((v.u >> 16) & 1u);
  return (short)(r >> 16);
}
__device__ __forceinline__ float sigm(float x) {
  float e = exp2f(-1.44269504f * x);
  return __builtin_amdgcn_rcpf(1.0f + e);
}
__device__ __forceinline__ float tanh_f(float x) {
  float a = __builtin_fabsf(x);
  float t = exp2f(-2.88539008f * a);
  float r = (1.0f - t) * __builtin_amdgcn_rcpf(1.0f + t);
  return __builtin_copysignf(r, x);
}
__device__ __forceinline__ f32x4 splat4(float b){ f32x4 v = {b,b,b,b}; return v; }

// ws layout (shorts for wp):
//  R1  [16 mem][4 nf][8 kc][64 l][8 e]  W_hh1 packed  (512KB)
//  R2a [16][2 gh][8 kc][64][8]          W_ih2         (256KB)
//  R2b [16][2][4][64][8]                W_hh2         (128KB)
//  R1i [16][4][8][64][8]                W_ih1         (512KB)
#define R1S   0
#define R2AS  262144
#define R2BS  393216
#define R1IS  458752
#define CTRL_B 1441792   // claim[xcd] @ dword xcd*32 ; ctr[g] @ dword 256+g*32 (128B spread)
#define H0X_B  1445888   // [2][16 grp][256 row][256 u] bf16 = 4MB
#define H1X_B  5640192   // [2][16 grp][256 row][128 u] bf16 = 2MB

// gate-pair packing: tile col = ul*2 + gp ; gate = gh*2 + gp
__global__ __launch_bounds__(256) void pack_w(
    const float* __restrict__ W_ih1, const float* __restrict__ W_hh1,
    const float* __restrict__ W_ih2, const float* __restrict__ W_hh2,
    short* __restrict__ wp) {
  int s = blockIdx.x * 256 + threadIdx.x;
  if (blockIdx.x == 0 && threadIdx.x < 256) {   // zero 4KB control region each launch
    unsigned* c = (unsigned*)((char*)wp + CTRL_B);
    #pragma unroll
    for (int k = 0; k < 4; ++k) c[threadIdx.x * 4 + k] = 0u;
  }
  if (s >= 90112) return;
  const float* src; int row, K, k0, l;
  if (s < 32768) {            // R1 <- W_hh1 [1024][256]
    int mm = s >> 11, r = s & 2047, nf = r >> 9, kc = (r >> 6) & 7; l = r & 63;
    int a = nf >> 1, gh = nf & 1, ul = (l & 15) >> 1, gp = l & 1;
    row = (gh*2+gp)*256 + mm*16 + a*8 + ul; K = 256; k0 = kc*32 + (l>>4)*8; src = W_hh1;
  } else if (s < 49152) {     // R2a <- W_ih2 [512][256]
    int s2 = s - 32768, mm = s2 >> 10, r = s2 & 1023, gh = r >> 9, kc = (r >> 6) & 7; l = r & 63;
    int ul = (l & 15) >> 1, gp = l & 1;
    row = (gh*2+gp)*128 + mm*8 + ul; K = 256; k0 = kc*32 + (l>>4)*8; src = W_ih2;
  } else if (s < 57344) {     // R2b <- W_hh2 [512][128]
    int s3 = s - 49152, mm = s3 >> 9, r = s3 & 511, gh = r >> 8, kc = (r >> 6) & 3; l = r & 63;
    int ul = (l & 15) >> 1, gp = l & 1;
    row = (gh*2+gp)*128 + mm*8 + ul; K = 128; k0 = kc*32 + (l>>4)*8; src = W_hh2;
  } else {                    // R1i <- W_ih1 [1024][256]
    int s4 = s - 57344, mm = s4 >> 11, r = s4 & 2047, nf = r >> 9, kc = (r >> 6) & 7; l = r & 63;
    int a = nf >> 1, gh = nf & 1, ul = (l & 15) >> 1, gp = l & 1;
    row = (gh*2+gp)*256 + mm*16 + a*8 + ul; K = 256; k0 = kc*32 + (l>>4)*8; src = W_ih1;
  }
  const float* p = src + (size_t)row * K + k0;
  bf16x8 o;
  #pragma unroll
  for (int e = 0; e < 8; ++e) o[e] = f2bf(p[e]);
  *(bf16x8*)(wp + (size_t)s * 8) = o;
}

// 256 blocks x 512 threads, 1 block/CU. 16 groups x 16 members, 256 rows/group.
// Iteration u computes layer1(u) AND layer2(u-1) (both consume a0 = h0(u-1)),
// then ONE group barrier publishes h0(u) + h1(u-1) together.
__global__ __launch_bounds__(512, 2) void lstm_persist(
    const float* __restrict__ emb, const float* __restrict__ b_ih1,
    const float* __restrict__ b_hh1, const float* __restrict__ b_ih2,
    const float* __restrict__ b_hh2, char* __restrict__ ws,
    float* __restrict__ out) {
  extern __shared__ __align__(16) short ldsW[];
  const short* wp = (const short*)ws;
  unsigned* ctrl = (unsigned*)(ws + CTRL_B);
  __shared__ unsigned s_gm;
  const int tid = threadIdx.x, w = tid >> 6, l = tid & 63, l15 = l & 15, l4 = l >> 4;
  const int ul = l15 >> 1, gp = l15 & 1;

  // claim a (group, member) slot on this block's own XCD -> same-XCD groups
  if (tid == 0) {
    unsigned xcc;
    asm volatile("s_getreg_b32 %0, hwreg(HW_REG_XCC_ID)" : "=s"(xcc));
    xcc &= 7u;
    unsigned slot = atomicAdd(&ctrl[xcc * 32], 1u);
    s_gm = ((xcc * 2u + ((slot >> 4) & 1u)) << 8) | (slot & 15u);
  }
  __syncthreads();
  const int group = s_gm >> 8, member = s_gm & 255;

  // copy this member's weight slices into LDS (56KB)
  {
    const char* wpB = (const char*)wp;
    #pragma unroll
    for (int it = 0; it < 7; ++it) {
      int byte = (tid + it * 512) * 16;
      const char* src;
      if (byte < 32768)      src = wpB + (size_t)R1S * 2  + member * 32768 + byte;
      else if (byte < 49152) src = wpB + (size_t)R2AS * 2 + member * 16384 + (byte - 32768);
      else                   src = wpB + (size_t)R2BS * 2 + member * 8192  + (byte - 49152);
      *(f32x4*)((char*)ldsW + byte) = *(const f32x4*)src;
    }
  }
  float b2[2];
  #pragma unroll
  for (int gh = 0; gh < 2; ++gh) {
    int rw = (gh*2+gp)*128 + member*8 + ul;
    b2[gh] = b_ih2[rw] + b_hh2[rw];
  }
  float b1[4];
  #pragma unroll
  for (int nf = 0; nf < 4; ++nf) {
    int rw = ((nf&1)*2+gp)*256 + member*16 + (nf>>1)*8 + ul;
    b1[nf] = b_ih1[rw] + b_hh1[rw];
  }
  __syncthreads();   // LDS weights ready

  // x1 = emb @ W_ih1^T + b1 for rows [group*256 + w*32, +32), kept in registers
  const int grow0 = group * 256;
  const int rw0 = w * 32;
  f32x4 x1[2][4];
  #pragma unroll
  for (int m = 0; m < 2; ++m)
    #pragma unroll
    for (int nf = 0; nf < 4; ++nf) x1[m][nf] = splat4(b1[nf]);
  #pragma unroll
  for (int kc = 0; kc < 8; ++kc) {
    bf16x8 af[2];
    #pragma unroll
    for (int m = 0; m < 2; ++m) {
      const float* ep = emb + (size_t)(grow0 + rw0 + m*16 + l15) * 256 + kc*32 + l4*8;
      f32x4 lo = *(const f32x4*)ep, hi = *(const f32x4*)(ep + 4);
      bf16x8 t8;
      #pragma unroll
      for (int e = 0; e < 4; ++e) { t8[e] = f2bf(lo[e]); t8[e+4] = f2bf(hi[e]); }
      af[m] = t8;
    }
    #pragma unroll
    for (int nf = 0; nf < 4; ++nf) {
      bf16x8 bb = *(const bf16x8*)(wp + R1IS + (((size_t)member*4 + nf)*8 + kc)*512 + l*8);
      x1[0][nf] = __builtin_amdgcn_mfma_f32_16x16x32_bf16(af[0], bb, x1[0][nf], 0, 0, 0);
      x1[1][nf] = __builtin_amdgcn_mfma_f32_16x16x32_bf16(af[1], bb, x1[1][nf], 0, 0, 0);
    }
  }

  bf16x8 a0[2][8], a1[2][4];
  const bf16x8 ZB = {0,0,0,0,0,0,0,0};
  #pragma unroll
  for (int m = 0; m < 2; ++m) {
    #pragma unroll
    for (int kc = 0; kc < 8; ++kc) a0[m][kc] = ZB;
    #pragma unroll
    for (int kc = 0; kc < 4; ++kc) a1[m][kc] = ZB;
  }
  float c0[2][2][2] = {};   // [m][a][rr]
  float c1[2][2] = {};      // [m][rr]

  unsigned* myctr = &ctrl[256 + group * 32];
  char* h0x = ws + H0X_B;
  char* h1x = ws + H1X_B;

  #pragma unroll 1
  for (int u = 0; u <= 128; ++u) {
    f32x4 acc1[2][4], acc2[2][2];
    // ---- layer1(u) MFMA: x1 + h0(u-1) @ W_hh1^T ----
    if (u < 128) {
      #pragma unroll
      for (int m = 0; m < 2; ++m)
        #pragma unroll
        for (int nf = 0; nf < 4; ++nf) acc1[m][nf] = x1[m][nf];
      #pragma unroll
      for (int nf = 0; nf < 4; ++nf)
        #pragma unroll
        for (int kc = 0; kc < 8; ++kc) {
          bf16x8 bb = *(const bf16x8*)(ldsW + (nf*8 + kc)*512 + l*8);
          acc1[0][nf] = __builtin_amdgcn_mfma_f32_16x16x32_bf16(a0[0][kc], bb, acc1[0][nf], 0,0,0);
          acc1[1][nf] = __builtin_amdgcn_mfma_f32_16x16x32_bf16(a0[1][kc], bb, acc1[1][nf], 0,0,0);
        }
    }
    // ---- layer2(u-1) MFMA: h0(u-1)@W_ih2^T + b2 + h1(u-2)@W_hh2^T (independent chain) ----
    if (u > 0) {
      #pragma unroll
      for (int m = 0; m < 2; ++m)
        #pragma unroll
        for (int gh = 0; gh < 2; ++gh) acc2[m][gh] = splat4(b2[gh]);
      #pragma unroll
      for (int gh = 0; gh < 2; ++gh)
        #pragma unroll
        for (int kc = 0; kc < 8; ++kc) {
          bf16x8 bb = *(const bf16x8*)(ldsW + 16384 + (gh*8 + kc)*512 + l*8);
          acc2[0][gh] = __builtin_amdgcn_mfma_f32_16x16x32_bf16(a0[0][kc], bb, acc2[0][gh], 0,0,0);
          acc2[1][gh] = __builtin_amdgcn_mfma_f32_16x16x32_bf16(a0[1][kc], bb, acc2[1][gh], 0,0,0);
        }
      #pragma unroll
      for (int gh = 0; gh < 2; ++gh)
        #pragma unroll
        for (int kc = 0; kc < 4; ++kc) {
          bf16x8 bb = *(const bf16x8*)(ldsW + 24576 + (gh*4 + kc)*512 + l*8);
          acc2[0][gh] = __builtin_amdgcn_mfma_f32_16x16x32_bf16(a1[0][kc], bb, acc2[0][gh], 0,0,0);
          acc2[1][gh] = __builtin_amdgcn_mfma_f32_16x16x32_bf16(a1[1][kc], bb, acc2[1][gh], 0,0,0);
        }
    }
    // ---- gates layer1 (dedup: lane gp computes rows gp*2+rr) ----
    if (u < 128) {
      char* h0w = h0x + ((size_t)(u & 1) * 16 + group) * 131072;
      #pragma unroll
      for (int m = 0; m < 2; ++m)
        #pragma unroll
        for (int a = 0; a < 2; ++a) {
          f32x4 v0 = acc1[m][a*2+0], v1 = acc1[m][a*2+1];
          #pragma unroll
          for (int rr = 0; rr < 2; ++rr) {
            float s0 = gp ? v0[rr] : v0[2+rr];
            float s1 = gp ? v1[rr] : v1[2+rr];
            float p0 = __shfl_xor(s0, 1, 64);
            float p1 = __shfl_xor(s1, 1, 64);
            float o0 = gp ? v0[2+rr] : v0[rr];
            float o1 = gp ? v1[2+rr] : v1[rr];
            float iv = gp ? p0 : o0, fv = gp ? o0 : p0;
            float gv = gp ? p1 : o1, ov = gp ? o1 : p1;
            float c = sigm(fv) * c0[m][a][rr] + sigm(iv) * tanh_f(gv);
            c0[m][a][rr] = c;
            float h = sigm(ov) * tanh_f(c);
            int row = rw0 + m*16 + l4*4 + gp*2 + rr;
            *(short*)(h0w + row*512 + (member*16 + a*8 + ul)*2) = f2bf(h);
          }
        }
    }
    // ---- gates layer2 (t = u-1) ----
    if (u > 0) {
      const int t = u - 1;
      char* h1w = h1x + ((size_t)(t & 1) * 16 + group) * 65536;
      #pragma unroll
      for (int m = 0; m < 2; ++m) {
        f32x4 v0 = acc2[m][0], v1 = acc2[m][1];
        #pragma unroll
        for (int rr = 0; rr < 2; ++rr) {
          float s0 = gp ? v0[rr] : v0[2+rr];
          float s1 = gp ? v1[rr] : v1[2+rr];
          float p0 = __shfl_xor(s0, 1, 64);
          float p1 = __shfl_xor(s1, 1, 64);
          float o0 = gp ? v0[2+rr] : v0[rr];
          float o1 = gp ? v1[2+rr] : v1[rr];
          float iv = gp ? p0 : o0, fv = gp ? o0 : p0;
          float gv = gp ? p1 : o1, ov = gp ? o1 : p1;
          float c = sigm(fv) * c1[m][rr] + sigm(iv) * tanh_f(gv);
          c1[m][rr] = c;
          float h = sigm(ov) * tanh_f(c);
          int row = rw0 + m*16 + l4*4 + gp*2 + rr;
          if (u < 128)
            *(short*)(h1w + row*256 + (member*8 + ul)*2) = f2bf(h);
          __builtin_nontemporal_store(
              h, out + (size_t)(grow0 + row) * 16384 + t*128 + member*8 + ul);
        }
      }
    }
    // ---- one group barrier per iteration: publish h0(u) + h1(u-1) ----
    if (u < 128) {
      __syncthreads();                       // drains vmcnt: stores visible in L2
      if (tid == 0) {
        __hip_atomic_fetch_add(myctr, 1u, __ATOMIC_RELAXED, __HIP_MEMORY_SCOPE_AGENT);
        unsigned tgt = 16u * (u + 1); int z = 0;
        while (__hip_atomic_load(myctr, __ATOMIC_RELAXED, __HIP_MEMORY_SCOPE_AGENT) < tgt) {
          __builtin_amdgcn_s_sleep(1);
          if (++z > (1 << 18)) break;        // escape hatch: fail visibly, never hang
        }
      }
      __syncthreads();
      asm volatile("buffer_inv sc0\n\ts_waitcnt vmcnt(0)" ::: "memory");
      const char* h0r = h0x + ((size_t)(u & 1) * 16 + group) * 131072;
      #pragma unroll
      for (int m = 0; m < 2; ++m)
        #pragma unroll
        for (int kc = 0; kc < 8; ++kc)
          a0[m][kc] = *(const bf16x8*)(h0r + (rw0 + m*16 + l15)*512 + kc*64 + l4*16);
      if (u >= 1) {
        const char* h1r = h1x + ((size_t)((u-1) & 1) * 16 + group) * 65536;
        #pragma unroll
        for (int m = 0; m < 2; ++m)
          #pragma unroll
          for (int kc = 0; kc < 4; ++kc)
            a1[m][kc] = *(const bf16x8*)(h1r + (rw0 + m*16 + l15)*256 + kc*64 + l4*16);
      }
    }
  }
}

extern "C" void kernel_launch(void* const* d_in, const int* in_sizes, int n_in,
                              void* d_out, int out_size, void* d_ws, size_t ws_size,
                              hipStream_t stream) {
  const float* emb   = (const float*)d_in[0];
  const float* W_ih1 = (const float*)d_in[1];
  const float* W_hh1 = (const float*)d_in[2];
  const float* b_ih1 = (const float*)d_in[3];
  const float* b_hh1 = (const float*)d_in[4];
  const float* W_ih2 = (const float*)d_in[5];
  const float* W_hh2 = (const float*)d_in[6];
  const float* b_ih2 = (const float*)d_in[7];
  const float* b_hh2 = (const float*)d_in[8];
  char* ws = (char*)d_ws;
  float* out = (float*)d_out;

  hipFuncSetAttribute((const void*)lstm_persist,
                      hipFuncAttributeMaxDynamicSharedMemorySize, 98304);
  pack_w<<<352, 256, 0, stream>>>(W_ih1, W_hh1, W_ih2, W_hh2, (short*)d_ws);
  lstm_persist<<<256, 512, 98304, stream>>>(emb, b_ih1, b_hh1, b_ih2, b_hh2, ws, out);
}